// Round 12
// baseline (1908.152 us; speedup 1.0000x reference)
//
#include <hip/hip_runtime.h>
#include <stdint.h>

#define NB   64
#define NPIX 1024
#define DIM  768
#define KTOP 4
#define REPS 16

// ---------------------------------------------------------------------------
// Kernel 1: sim = z.q/sqrt(D). Unchanged (absmax-0 proven; ~25 us measured).
// ---------------------------------------------------------------------------
__global__ __launch_bounds__(256) void sgatt_sim(const float* __restrict__ z,
                                                 const float* __restrict__ q,
                                                 float* __restrict__ sim) {
    const int b    = blockIdx.y;
    const int lane = threadIdx.x & 63;
    const int wave = threadIdx.x >> 6;
    const float4* qv = reinterpret_cast<const float4*>(q + (size_t)b * DIM);
    const float4 q0 = qv[lane], q1 = qv[lane + 64], q2 = qv[lane + 128];
    const float rt = sqrtf((float)DIM);
#pragma unroll
    for (int r = 0; r < 4; ++r) {
        const int row = blockIdx.x * 16 + wave * 4 + r;
        const float4* zv =
            reinterpret_cast<const float4*>(z + (size_t)(b * NPIX + row) * DIM);
        const float4 z0 = zv[lane], z1 = zv[lane + 64], z2 = zv[lane + 128];
        double acc = (double)z0.x * q0.x + (double)z0.y * q0.y +
                     (double)z0.z * q0.z + (double)z0.w * q0.w;
        acc += (double)z1.x * q1.x + (double)z1.y * q1.y +
               (double)z1.z * q1.z + (double)z1.w * q1.w;
        acc += (double)z2.x * q2.x + (double)z2.y * q2.y +
               (double)z2.z * q2.z + (double)z2.w * q2.w;
#pragma unroll
        for (int o = 32; o > 0; o >>= 1) acc += __shfl_xor(acc, o);
        if (lane == 0) sim[b * NPIX + row] = (float)acc / rt;
    }
}

__device__ inline int uf_find(volatile int* p, int x) {
    int px = p[x];
    while (px != x) {
        const int g = p[px];
        if (g != px) p[x] = g;
        x = g;
        px = p[x];
    }
    return x;
}

__device__ inline void uf_union(volatile int* p, int a, int b) {
    while (true) {
        a = uf_find(p, a);
        b = uf_find(p, b);
        if (a == b) return;
        const int hi = a > b ? a : b;
        const int lo = a ^ b ^ hi;
        const int old = atomicCAS((int*)&p[hi], hi, lo);
        if (old == hi) return;
        a = old; b = lo;
    }
}

// ---------------------------------------------------------------------------
// Region pipeline body, shared by ablation variants (DBL>=0) and canonical.
// DBL: 0=baseline, 1=double unions, 2=double histogram, 3=double root-chase,
// 4=double area/ssum accumulation. Doubled work goes to s_bufC (scratch LDS);
// atomics are side-effect-safe vs DCE, the read-only chase uses asm keepalive.
// ---------------------------------------------------------------------------
template <int DBL, int NREP>
__device__ void region_body(const float* __restrict__ sim,
                            float* __restrict__ outp) {
    const int b    = blockIdx.x;
    const int t    = threadIdx.x;
    const int lane = t & 63;
    const int wid  = t >> 6;

    __shared__ int   s_bufA[NPIX];
    __shared__ int   s_bufB[NPIX];
    __shared__ int   s_bufC[2048];        // ablation scratch (zeroed per rep)
    __shared__ float s_wA[4], s_wB[4];
    __shared__ float s_avv[4];
    __shared__ int   s_avi[4];
    __shared__ float s_smin, s_smax;
    __shared__ int   s_thr;
    __shared__ int   s_top[KTOP];

    for (int rep = 0; rep < NREP; ++rep) {

    s_bufB[t] = 0;
    if (t < NPIX / 32) s_bufB[256 + t] = 0;
#pragma unroll
    for (int k = 0; k < 8; ++k) s_bufC[t * 8 + k] = 0;   // uniform across DBL
    int* s_hist = s_bufB;
    unsigned int* s_mbits = reinterpret_cast<unsigned int*>(s_bufB + 256);

    // ---- phase 1: load sim, min/max ------------------------------------
    const float4 sv4 =
        reinterpret_cast<const float4*>(sim + (size_t)b * NPIX)[t];
    const float svj[4] = {sv4.x, sv4.y, sv4.z, sv4.w};
    float mn = fminf(fminf(svj[0], svj[1]), fminf(svj[2], svj[3]));
    float mx = fmaxf(fmaxf(svj[0], svj[1]), fmaxf(svj[2], svj[3]));
#pragma unroll
    for (int o = 32; o > 0; o >>= 1) {
        mn = fminf(mn, __shfl_xor(mn, o));
        mx = fmaxf(mx, __shfl_xor(mx, o));
    }
    if (lane == 0) { s_wA[wid] = mn; s_wB[wid] = mx; }
    __syncthreads();
    if (t == 0) {
        float a = s_wA[0], c = s_wB[0];
        for (int w = 1; w < 4; ++w) { a = fminf(a, s_wA[w]); c = fmaxf(c, s_wB[w]); }
        s_smin = a; s_smax = c;
    }
    __syncthreads();

    // ---- phase 2: sal + u8 + histogram ---------------------------------
    const float smin = s_smin;
    const float den0 = __fadd_rn(__fsub_rn(s_smax, smin), 1e-6f);
    float salj[4];
    int u8j[4];
#pragma unroll
    for (int j = 0; j < 4; ++j) {
        salj[j] = __fdiv_rn(__fsub_rn(svj[j], smin), den0);
        int u = (int)floorf(__fmul_rn(salj[j], 255.0f));
        u8j[j] = min(max(u, 0), 255);
        atomicAdd(&s_hist[u8j[j]], 1);
        if (DBL == 2) atomicAdd(&s_bufC[u8j[j]], 1);     // doubled histogram
    }
    __syncthreads();

    // ---- phase 3: Otsu (shfl scan) -------------------------------------
    {
        const float p = __fmul_rn((float)s_hist[t], 1.0f / 1024.0f);
        float w0 = p;
        float mu = __fmul_rn(p, (float)t);
#pragma unroll
        for (int o = 1; o < 64; o <<= 1) {
            const float aw = __shfl_up(w0, o);
            const float am = __shfl_up(mu, o);
            if (lane >= o) { w0 = __fadd_rn(w0, aw); mu = __fadd_rn(mu, am); }
        }
        if (lane == 63) { s_wA[wid] = w0; s_wB[wid] = mu; }
        __syncthreads();
        float mut = 0.0f;
        for (int w = 0; w < 4; ++w) mut = __fadd_rn(mut, s_wB[w]);
        for (int w = 0; w < wid; ++w) {
            w0 = __fadd_rn(w0, s_wA[w]);
            mu = __fadd_rn(mu, s_wB[w]);
        }
        const float num = __fsub_rn(__fmul_rn(mut, w0), mu);
        const float dn  = __fadd_rn(__fmul_rn(w0, __fsub_rn(1.0f, w0)), 1e-12f);
        float v  = __fdiv_rn(__fmul_rn(num, num), dn);
        int   idx = t;
#pragma unroll
        for (int o = 32; o > 0; o >>= 1) {
            const float v2 = __shfl_xor(v, o);
            const int   i2 = __shfl_xor(idx, o);
            if (v2 > v || (v2 == v && i2 < idx)) { v = v2; idx = i2; }
        }
        if (lane == 0) { s_avv[wid] = v; s_avi[wid] = idx; }
    }
    __syncthreads();
    if (t == 0) {
        float bv = s_avv[0]; int bi = s_avi[0];
        for (int w = 1; w < 4; ++w)
            if (s_avv[w] > bv || (s_avv[w] == bv && s_avi[w] < bi)) {
                bv = s_avv[w]; bi = s_avi[w];
            }
        s_thr = bi;
    }
    __syncthreads();
    const int thr = s_thr;

    // ---- phase 4: mask + parent init -----------------------------------
    int* s_par = s_bufA;
    int mj[4];
#pragma unroll
    for (int j = 0; j < 4; ++j) {
        const int px = 4*t + j;
        mj[j] = (u8j[j] > thr) ? 1 : 0;
        const int pinit = (j > 0 && mj[j] && mj[j-1]) ? (px - 1) : px;
        s_par[px] = pinit;
        if (DBL == 1) s_bufC[px] = pinit;                // scratch parent copy
        if (mj[j]) atomicOr(&s_mbits[px >> 5], 1u << (px & 31));
    }
    __syncthreads();

    // ---- phase 5: unions ------------------------------------------------
#define ONMASK(p) ((s_mbits[(p) >> 5] >> ((p) & 31)) & 1u)
#pragma unroll
    for (int j = 0; j < 4; ++j) {
        if (!mj[j]) continue;
        const int px = 4*t + j;
        const int r = px >> 5, c = px & 31;
        if (j == 0 && c > 0 && ONMASK(px - 1)) uf_union(s_par, px, px - 1);
        if (r > 0) {
            if (c > 0 && ONMASK(px - 33)) uf_union(s_par, px, px - 33);
            if (ONMASK(px - 32))          uf_union(s_par, px, px - 32);
            if (c < 31 && ONMASK(px - 31)) uf_union(s_par, px, px - 31);
        }
    }
    if (DBL == 1) {                                      // doubled unions
        __syncthreads();
#pragma unroll
        for (int j = 0; j < 4; ++j) {
            if (!mj[j]) continue;
            const int px = 4*t + j;
            const int r = px >> 5, c = px & 31;
            if (j == 0 && c > 0 && ONMASK(px - 1)) uf_union(s_bufC, px, px - 1);
            if (r > 0) {
                if (c > 0 && ONMASK(px - 33)) uf_union(s_bufC, px, px - 33);
                if (ONMASK(px - 32))          uf_union(s_bufC, px, px - 32);
                if (c < 31 && ONMASK(px - 31)) uf_union(s_bufC, px, px - 31);
            }
        }
    }
#undef ONMASK
    __syncthreads();

    // ---- phase 6: root chase (lockstep) --------------------------------
    int labj[4];
    {
        int cur[4], par[4];
#pragma unroll
        for (int j = 0; j < 4; ++j) cur[j] = 4*t + j;
#pragma unroll
        for (int j = 0; j < 4; ++j) par[j] = s_par[cur[j]];
        while (true) {
            bool any = false;
#pragma unroll
            for (int j = 0; j < 4; ++j) any |= (par[j] != cur[j]);
            if (!any) break;
#pragma unroll
            for (int j = 0; j < 4; ++j) cur[j] = par[j];
#pragma unroll
            for (int j = 0; j < 4; ++j) par[j] = s_par[cur[j]];
        }
#pragma unroll
        for (int j = 0; j < 4; ++j) labj[j] = mj[j] ? (cur[j] + 1) : 0;
    }
    if (DBL == 3) {                                      // doubled chase
        int cur[4], par[4];
#pragma unroll
        for (int j = 0; j < 4; ++j) cur[j] = 4*t + j;
#pragma unroll
        for (int j = 0; j < 4; ++j) par[j] = s_par[cur[j]];
        while (true) {
            bool any = false;
#pragma unroll
            for (int j = 0; j < 4; ++j) any |= (par[j] != cur[j]);
            if (!any) break;
#pragma unroll
            for (int j = 0; j < 4; ++j) cur[j] = par[j];
#pragma unroll
            for (int j = 0; j < 4; ++j) par[j] = s_par[cur[j]];
        }
#pragma unroll
        for (int j = 0; j < 4; ++j)
            asm volatile("" :: "v"(cur[j]));             // keep-alive, no DCE
    }
    __syncthreads();

    // ---- overlay: area/ssum --------------------------------------------
    float* s_ssum = reinterpret_cast<float*>(s_bufA);
    int*   s_area = s_bufB;
#pragma unroll
    for (int j = 0; j < 4; ++j) { s_area[4*t + j] = 0; s_ssum[4*t + j] = 0.0f; }
    __syncthreads();
#pragma unroll
    for (int j = 0; j < 4; ++j) {
        if (mj[j]) {
            atomicAdd(&s_area[labj[j] - 1], 1);
            atomicAdd(&s_ssum[labj[j] - 1], salj[j]);
            if (DBL == 4) {                              // doubled accumulation
                atomicAdd(&s_bufC[labj[j] - 1], 1);
                atomicAdd(reinterpret_cast<float*>(s_bufC) + 1024 + labj[j] - 1,
                          salj[j]);
            }
        }
    }
    __syncthreads();

    // ---- phase 7: top-4 on wave 0 --------------------------------------
    if (wid == 0) {
        unsigned long long key[16];
#pragma unroll
        for (int i = 0; i < 16; ++i) {
            const int idx = lane * 16 + i;
            const int a = s_area[idx];
            key[i] = 0ull;
            if (a >= 21) {
                const float mean = __fdiv_rn(s_ssum[idx], (float)a);
                key[i] = ((unsigned long long)__float_as_uint(mean) << 32) |
                         (unsigned long long)(0xFFFFFFFFu - (unsigned)(idx + 1));
            }
        }
        for (int k = 0; k < KTOP; ++k) {
            unsigned long long v = key[0];
#pragma unroll
            for (int i = 1; i < 16; ++i) v = (key[i] > v) ? key[i] : v;
#pragma unroll
            for (int o = 32; o > 0; o >>= 1) {
                const unsigned long long w = __shfl_xor(v, o);
                if (w > v) v = w;
            }
            if (lane == 0)
                s_top[k] = (v != 0ull)
                               ? (int)(0xFFFFFFFFu - (unsigned)(v & 0xFFFFFFFFull))
                               : -1;
#pragma unroll
            for (int i = 0; i < 16; ++i)
                if (key[i] == v && v != 0ull) key[i] = 0ull;
        }
    }
    __syncthreads();

    // ---- phase 8: write ------------------------------------------------
    float* ob = outp + (size_t)b * 5 * NPIX;
    int anyr[4] = {0, 0, 0, 0};
#pragma unroll
    for (int k = 0; k < KTOP; ++k) {
        const int tl = s_top[k];
        float4 o;
        float* op = reinterpret_cast<float*>(&o);
#pragma unroll
        for (int j = 0; j < 4; ++j) {
            const int match = (tl >= 0 && labj[j] == tl) ? 1 : 0;
            anyr[j] |= match;
            op[j] = (float)match;
        }
        reinterpret_cast<float4*>(ob + (size_t)k * NPIX)[t] = o;
    }
    {
        float4 o;
        float* op = reinterpret_cast<float*>(&o);
#pragma unroll
        for (int j = 0; j < 4; ++j) op[j] = anyr[j] ? 0.0f : 1.0f;
        reinterpret_cast<float4*>(ob + (size_t)KTOP * NPIX)[t] = o;
    }

    __syncthreads();
    }  // rep loop
}

template <int DBL>
__global__ __launch_bounds__(256) void sgatt_region_abl(const float* __restrict__ sim,
                                                        float* __restrict__ scratch) {
    region_body<DBL, REPS>(sim, scratch);
}

__global__ __launch_bounds__(256) void sgatt_region(const float* __restrict__ sim,
                                                    float* __restrict__ out) {
    region_body<0, 1>(sim, out);
}

// ---------------------------------------------------------------------------
extern "C" void kernel_launch(void* const* d_in, const int* in_sizes, int n_in,
                              void* d_out, int out_size, void* d_ws, size_t ws_size,
                              hipStream_t stream) {
    const float* z = (const float*)d_in[0];
    const float* q = (const float*)d_in[1];
    float* out = (float*)d_out;
    float* sim = (float*)d_ws;  // 256 KiB

    dim3 g1(NPIX / 16, NB);
    sgatt_sim<<<g1, 256, 0, stream>>>(z, q, sim);

    // DIAGNOSTIC: within-probe phase ablation (work-doubling), results read
    // from rocprof dispatch durations. Scratch is never read; canonical
    // output below is unaffected.
    const size_t scratch_off = 1u << 20;                     // 1 MiB
    const size_t scratch_need = scratch_off + (size_t)NB * 5 * NPIX * 4;
    if (ws_size >= scratch_need) {
        float* scratch = (float*)((char*)d_ws + scratch_off);
        sgatt_region_abl<0><<<NB, 256, 0, stream>>>(sim, scratch);
        sgatt_region_abl<1><<<NB, 256, 0, stream>>>(sim, scratch);
        sgatt_region_abl<2><<<NB, 256, 0, stream>>>(sim, scratch);
        sgatt_region_abl<3><<<NB, 256, 0, stream>>>(sim, scratch);
        sgatt_region_abl<4><<<NB, 256, 0, stream>>>(sim, scratch);
    }

    sgatt_region<<<NB, 256, 0, stream>>>(sim, out);
}

// Round 13
// 83.909 us; speedup vs baseline: 22.7406x; 22.7406x over previous
//
#include <hip/hip_runtime.h>
#include <stdint.h>

#define NB   64
#define NPIX 1024
#define DIM  768
#define KTOP 4

// ---------------------------------------------------------------------------
// Kernel 1: sim = z.q/sqrt(D). Unchanged (absmax-0 proven; ~25us, supply-bound
// at ~8 TB/s effective: 99MB HBM + ~100MB L3 per dispatch).
// ---------------------------------------------------------------------------
__global__ __launch_bounds__(256) void sgatt_sim(const float* __restrict__ z,
                                                 const float* __restrict__ q,
                                                 float* __restrict__ sim) {
    const int b    = blockIdx.y;
    const int lane = threadIdx.x & 63;
    const int wave = threadIdx.x >> 6;
    const float4* qv = reinterpret_cast<const float4*>(q + (size_t)b * DIM);
    const float4 q0 = qv[lane], q1 = qv[lane + 64], q2 = qv[lane + 128];
    const float rt = sqrtf((float)DIM);
#pragma unroll
    for (int r = 0; r < 4; ++r) {
        const int row = blockIdx.x * 16 + wave * 4 + r;
        const float4* zv =
            reinterpret_cast<const float4*>(z + (size_t)(b * NPIX + row) * DIM);
        const float4 z0 = zv[lane], z1 = zv[lane + 64], z2 = zv[lane + 128];
        double acc = (double)z0.x * q0.x + (double)z0.y * q0.y +
                     (double)z0.z * q0.z + (double)z0.w * q0.w;
        acc += (double)z1.x * q1.x + (double)z1.y * q1.y +
               (double)z1.z * q1.z + (double)z1.w * q1.w;
        acc += (double)z2.x * q2.x + (double)z2.y * q2.y +
               (double)z2.z * q2.z + (double)z2.w * q2.w;
#pragma unroll
        for (int o = 32; o > 0; o >>= 1) acc += __shfl_xor(acc, o);
        if (lane == 0) sim[b * NPIX + row] = (float)acc / rt;
    }
}

// ---------------------------------------------------------------------------
// Lock-free union-find in LDS with path halving (ablation-proven ~free).
// ---------------------------------------------------------------------------
__device__ inline int uf_find(volatile int* p, int x) {
    int px = p[x];
    while (px != x) {
        const int g = p[px];
        if (g != px) p[x] = g;   // path halving (benign race)
        x = g;
        px = p[x];
    }
    return x;
}

__device__ inline void uf_union(volatile int* p, int a, int b) {
    while (true) {
        a = uf_find(p, a);
        b = uf_find(p, b);
        if (a == b) return;
        const int hi = a > b ? a : b;
        const int lo = a ^ b ^ hi;
        const int old = atomicCAS((int*)&p[hi], hi, lo);
        if (old == hi) return;
        a = old; b = lo;
    }
}

__device__ inline unsigned long long umax64(unsigned long long a,
                                            unsigned long long b) {
    return a > b ? a : b;
}
__device__ inline unsigned long long umin64(unsigned long long a,
                                            unsigned long long b) {
    return a < b ? a : b;
}

// ---------------------------------------------------------------------------
// Kernel 2: SINGLE-WAVE region (64 threads, 16 px/lane). The round-12 ablation
// showed all bulk phases (unions/chase/hist/accum) are ~free; the cost is the
// multi-wave skeleton. This version: all reductions in-wave (no cross-wave
// LDS combines, no t==0 sections), 7 one-wave barriers, top-4 via a bitonic
// merge tree (6 levels instead of 4x6).
// px(i) = (i>>2)*256 + 4*lane + (i&3), i in [0,16).
// ---------------------------------------------------------------------------
__global__ __launch_bounds__(64) void sgatt_region(const float* __restrict__ sim,
                                                   float* __restrict__ out) {
    const int b = blockIdx.x;
    const int l = threadIdx.x;            // one wave: thread == lane

    __shared__ int s_bufA[NPIX];          // s_par -> s_ssum(float)
    __shared__ int s_bufB[NPIX];          // hist+mbits -> s_area

    // zero hist(256)+mbits(32) = bufB[0:288]
    s_bufB[l] = 0; s_bufB[l + 64] = 0; s_bufB[l + 128] = 0; s_bufB[l + 192] = 0;
    if (l < 32) s_bufB[256 + l] = 0;
    int* s_hist = s_bufB;
    unsigned int* s_mbits = reinterpret_cast<unsigned int*>(s_bufB + 256);

    // ---- phase 1: load 16 sim values, in-wave min/max --------------------
    const float4* sb = reinterpret_cast<const float4*>(sim + (size_t)b * NPIX);
    float svj[16];
    {
        const float4 v0 = sb[l], v1 = sb[l + 64], v2 = sb[l + 128],
                     v3 = sb[l + 192];
        svj[0]=v0.x; svj[1]=v0.y; svj[2]=v0.z; svj[3]=v0.w;
        svj[4]=v1.x; svj[5]=v1.y; svj[6]=v1.z; svj[7]=v1.w;
        svj[8]=v2.x; svj[9]=v2.y; svj[10]=v2.z; svj[11]=v2.w;
        svj[12]=v3.x; svj[13]=v3.y; svj[14]=v3.z; svj[15]=v3.w;
    }
    float mn = svj[0], mx = svj[0];
#pragma unroll
    for (int i = 1; i < 16; ++i) {
        mn = fminf(mn, svj[i]);
        mx = fmaxf(mx, svj[i]);
    }
#pragma unroll
    for (int o = 32; o > 0; o >>= 1) {
        mn = fminf(mn, __shfl_xor(mn, o));
        mx = fmaxf(mx, __shfl_xor(mx, o));
    }

    // ---- phase 2: sal + u8 (exact fp32, no FMA) --------------------------
    const float den0 = __fadd_rn(__fsub_rn(mx, mn), 1e-6f);
    float salj[16];
    int u8j[16];
#pragma unroll
    for (int i = 0; i < 16; ++i) {
        salj[i] = __fdiv_rn(__fsub_rn(svj[i], mn), den0);
        int u = (int)floorf(__fmul_rn(salj[i], 255.0f));
        u8j[i] = min(max(u, 0), 255);
    }
    __syncthreads();                       // zero-init visible
#pragma unroll
    for (int i = 0; i < 16; ++i) atomicAdd(&s_hist[u8j[i]], 1);
    __syncthreads();

    // ---- phase 3: Otsu — lane owns bins 4l..4l+3. All partial sums are
    // multiples of 2^-10 with numerators < 2^24 -> exact in fp32 under any
    // association (incl. prefix = inclusive - own, both representable), so
    // results are bit-identical to the reference cumsum.
    int thr;
    {
        const float p0 = __fmul_rn((float)s_hist[4*l + 0], 1.0f / 1024.0f);
        const float p1 = __fmul_rn((float)s_hist[4*l + 1], 1.0f / 1024.0f);
        const float p2 = __fmul_rn((float)s_hist[4*l + 2], 1.0f / 1024.0f);
        const float p3 = __fmul_rn((float)s_hist[4*l + 3], 1.0f / 1024.0f);
        const float cw0 = p0;
        const float cw1 = __fadd_rn(cw0, p1);
        const float cw2 = __fadd_rn(cw1, p2);
        const float cw3 = __fadd_rn(cw2, p3);
        const float q0 = __fmul_rn(p0, (float)(4*l + 0));
        const float q1 = __fmul_rn(p1, (float)(4*l + 1));
        const float q2 = __fmul_rn(p2, (float)(4*l + 2));
        const float q3 = __fmul_rn(p3, (float)(4*l + 3));
        const float cm0 = q0;
        const float cm1 = __fadd_rn(cm0, q1);
        const float cm2 = __fadd_rn(cm1, q2);
        const float cm3 = __fadd_rn(cm2, q3);
        float sw = cw3, sm = cm3;          // inclusive wave scan of lane totals
#pragma unroll
        for (int o = 1; o < 64; o <<= 1) {
            const float aw = __shfl_up(sw, o);
            const float am = __shfl_up(sm, o);
            if (l >= o) { sw = __fadd_rn(sw, aw); sm = __fadd_rn(sm, am); }
        }
        const float mut = __shfl(sm, 63);
        const float pw = __fsub_rn(sw, cw3);   // exclusive prefixes (exact)
        const float pm = __fsub_rn(sm, cm3);

        float bv = -1.0f;                      // sigma >= 0 always
        int bi = 4*l;
        const float cw[4] = {cw0, cw1, cw2, cw3};
        const float cm[4] = {cm0, cm1, cm2, cm3};
#pragma unroll
        for (int k = 0; k < 4; ++k) {
            const float w0k = __fadd_rn(pw, cw[k]);
            const float muk = __fadd_rn(pm, cm[k]);
            const float num = __fsub_rn(__fmul_rn(mut, w0k), muk);
            const float dnm =
                __fadd_rn(__fmul_rn(w0k, __fsub_rn(1.0f, w0k)), 1e-12f);
            const float v = __fdiv_rn(__fmul_rn(num, num), dnm);
            if (v > bv) { bv = v; bi = 4*l + k; }   // ascending k: first-index
        }
#pragma unroll
        for (int o = 32; o > 0; o >>= 1) {
            const float v2 = __shfl_xor(bv, o);
            const int   i2 = __shfl_xor(bi, o);
            if (v2 > bv || (v2 == bv && i2 < bi)) { bv = v2; bi = i2; }
        }
        thr = bi;
    }

    // ---- phase 4: mask bits + parent init + mbits ------------------------
    int* s_par = s_bufA;
    int mmask = 0;
#pragma unroll
    for (int i = 0; i < 16; ++i)
        if (u8j[i] > thr) mmask |= (1 << i);
#pragma unroll
    for (int q = 0; q < 4; ++q) {
        const int nib = (mmask >> (4*q)) & 0xF;
#pragma unroll
        for (int j = 0; j < 4; ++j) {
            const int px = q*256 + 4*l + j;
            const int on  = (nib >> j) & 1;
            const int pon = (j > 0) ? ((nib >> (j - 1)) & 1) : 0;
            // j>0 => px-1 is always same row (4l+j mod 32 != 0): W edge as
            // plain store under exclusive ownership (round-10 invariant).
            s_par[px] = (on && pon) ? (px - 1) : px;
        }
        if (nib)
            atomicOr(&s_mbits[(q*256 + 4*l) >> 5],
                     (unsigned)nib << ((4*l) & 31));
    }
    __syncthreads();

    // ---- phase 5: cross-boundary unions (ablation: ~free) ----------------
#define ONMASK(p) ((s_mbits[(p) >> 5] >> ((p) & 31)) & 1u)
#pragma unroll
    for (int i = 0; i < 16; ++i) {
        if (!((mmask >> i) & 1)) continue;
        const int px = ((i >> 2) << 8) + 4*l + (i & 3);
        const int r = px >> 5, c = px & 31;
        if ((i & 3) == 0 && c > 0 && ONMASK(px - 1)) uf_union(s_par, px, px - 1);
        if (r > 0) {
            if (c > 0 && ONMASK(px - 33)) uf_union(s_par, px, px - 33);
            if (ONMASK(px - 32))          uf_union(s_par, px, px - 32);
            if (c < 31 && ONMASK(px - 31)) uf_union(s_par, px, px - 31);
        }
    }
#undef ONMASK
    __syncthreads();

    // ---- phase 6: lockstep root chase (16 chains) -------------------------
    int labj[16];
    {
        int cur[16], par[16];
#pragma unroll
        for (int i = 0; i < 16; ++i) cur[i] = ((i >> 2) << 8) + 4*l + (i & 3);
#pragma unroll
        for (int i = 0; i < 16; ++i) par[i] = s_par[cur[i]];
        while (true) {
            bool any = false;
#pragma unroll
            for (int i = 0; i < 16; ++i) any |= (par[i] != cur[i]);
            if (!any) break;
#pragma unroll
            for (int i = 0; i < 16; ++i) cur[i] = par[i];
#pragma unroll
            for (int i = 0; i < 16; ++i) par[i] = s_par[cur[i]];
        }
#pragma unroll
        for (int i = 0; i < 16; ++i)
            labj[i] = ((mmask >> i) & 1) ? (cur[i] + 1) : 0;
    }
    __syncthreads();   // done with s_par / mbits -> overlay

    // ---- overlay: zero area/ssum (conflict-free l+64i), accumulate -------
    float* s_ssum = reinterpret_cast<float*>(s_bufA);   // [label-1]
    int*   s_area = s_bufB;                             // [label-1]
#pragma unroll
    for (int i = 0; i < 16; ++i) { s_area[l + 64*i] = 0; s_ssum[l + 64*i] = 0.0f; }
    __syncthreads();
#pragma unroll
    for (int i = 0; i < 16; ++i) {
        if ((mmask >> i) & 1) {
            atomicAdd(&s_area[labj[i] - 1], 1);
            atomicAdd(&s_ssum[labj[i] - 1], salj[i]);
        }
    }
    __syncthreads();

    // ---- phase 7: top-4 via per-lane sorted list + bitonic merge tree ----
    // valid <=> area >= 21; mean > 0 -> float bits order-preserving; ~label
    // in low word -> ties pick lower label. Keys unique => bitonic-merge
    // top-4 == repeated extract-max (bit-identical selection & order).
    unsigned long long k0 = 0, k1 = 0, k2 = 0, k3 = 0;
#pragma unroll
    for (int i = 0; i < 16; ++i) {
        const int idx = l + 64*i;                 // label = idx+1
        const int a = s_area[idx];
        unsigned long long key = 0ull;
        if (a >= 21) {
            const float mean = __fdiv_rn(s_ssum[idx], (float)a);
            key = ((unsigned long long)__float_as_uint(mean) << 32) |
                  (unsigned long long)(0xFFFFFFFFu - (unsigned)(idx + 1));
        }
        const bool g0 = key > k0, g1 = key > k1, g2 = key > k2, g3 = key > k3;
        const unsigned long long o0 = k0, o1 = k1, o2 = k2;
        k0 = g0 ? key : k0;
        k1 = g0 ? o0 : (g1 ? key : k1);
        k2 = g1 ? o1 : (g2 ? key : k2);
        k3 = g2 ? o2 : (g3 ? key : k3);
    }
#pragma unroll
    for (int o = 32; o > 0; o >>= 1) {
        const unsigned long long p0 = __shfl_xor(k0, o);
        const unsigned long long p1 = __shfl_xor(k1, o);
        const unsigned long long p2 = __shfl_xor(k2, o);
        const unsigned long long p3 = __shfl_xor(k3, o);
        // bitonic: (k0..k3 desc) ++ reverse(p0..p3 desc); keep top half
        const unsigned long long t0 = umax64(k0, p3);
        const unsigned long long t1 = umax64(k1, p2);
        const unsigned long long t2 = umax64(k2, p1);
        const unsigned long long t3 = umax64(k3, p0);
        const unsigned long long u0 = umax64(t0, t2), u2 = umin64(t0, t2);
        const unsigned long long u1 = umax64(t1, t3), u3 = umin64(t1, t3);
        k0 = umax64(u0, u1); k1 = umin64(u0, u1);
        k2 = umax64(u2, u3); k3 = umin64(u2, u3);
    }
    int tlv[KTOP];
    tlv[0] = k0 ? (int)(0xFFFFFFFFu - (unsigned)(k0 & 0xFFFFFFFFull)) : -1;
    tlv[1] = k1 ? (int)(0xFFFFFFFFu - (unsigned)(k1 & 0xFFFFFFFFull)) : -1;
    tlv[2] = k2 ? (int)(0xFFFFFFFFu - (unsigned)(k2 & 0xFFFFFFFFull)) : -1;
    tlv[3] = k3 ? (int)(0xFFFFFFFFu - (unsigned)(k3 & 0xFFFFFFFFull)) : -1;

    // ---- phase 8: write regions + background (float4 stores) -------------
    float* ob = out + (size_t)b * 5 * NPIX;
    int anyr = 0;
#pragma unroll
    for (int k = 0; k < KTOP; ++k) {
        const int tlk = tlv[k];
#pragma unroll
        for (int q = 0; q < 4; ++q) {
            float4 o;
            float* op = reinterpret_cast<float*>(&o);
#pragma unroll
            for (int j = 0; j < 4; ++j) {
                const int i = 4*q + j;
                const int match = (tlk >= 0 && labj[i] == tlk) ? 1 : 0;
                anyr |= match << i;
                op[j] = (float)match;
            }
            reinterpret_cast<float4*>(ob + (size_t)k * NPIX + q*256)[l] = o;
        }
    }
#pragma unroll
    for (int q = 0; q < 4; ++q) {
        float4 o;
        float* op = reinterpret_cast<float*>(&o);
#pragma unroll
        for (int j = 0; j < 4; ++j)
            op[j] = ((anyr >> (4*q + j)) & 1) ? 0.0f : 1.0f;
        reinterpret_cast<float4*>(ob + (size_t)KTOP * NPIX + q*256)[l] = o;
    }
}

// ---------------------------------------------------------------------------
extern "C" void kernel_launch(void* const* d_in, const int* in_sizes, int n_in,
                              void* d_out, int out_size, void* d_ws, size_t ws_size,
                              hipStream_t stream) {
    const float* z = (const float*)d_in[0];
    const float* q = (const float*)d_in[1];
    float* out = (float*)d_out;
    float* sim = (float*)d_ws;  // NB*NPIX floats = 256 KiB

    dim3 g1(NPIX / 16, NB);
    sgatt_sim<<<g1, 256, 0, stream>>>(z, q, sim);
    sgatt_region<<<NB, 64, 0, stream>>>(sim, out);
}

// Round 14
// 55.808 us; speedup vs baseline: 34.1913x; 1.5035x over previous
//
#include <hip/hip_runtime.h>
#include <stdint.h>

#define NB   64
#define NPIX 1024
#define DIM  768
#define KTOP 4

// ---------------------------------------------------------------------------
// Kernel 1: sim = z.q/sqrt(D). Unchanged (absmax-0 proven; ~25us measured,
// supply-bound: 99MB HBM + ~100MB L3 per dispatch = ~8 TB/s effective).
// ---------------------------------------------------------------------------
__global__ __launch_bounds__(256) void sgatt_sim(const float* __restrict__ z,
                                                 const float* __restrict__ q,
                                                 float* __restrict__ sim) {
    const int b    = blockIdx.y;
    const int lane = threadIdx.x & 63;
    const int wave = threadIdx.x >> 6;
    const float4* qv = reinterpret_cast<const float4*>(q + (size_t)b * DIM);
    const float4 q0 = qv[lane], q1 = qv[lane + 64], q2 = qv[lane + 128];
    const float rt = sqrtf((float)DIM);
#pragma unroll
    for (int r = 0; r < 4; ++r) {
        const int row = blockIdx.x * 16 + wave * 4 + r;
        const float4* zv =
            reinterpret_cast<const float4*>(z + (size_t)(b * NPIX + row) * DIM);
        const float4 z0 = zv[lane], z1 = zv[lane + 64], z2 = zv[lane + 128];
        double acc = (double)z0.x * q0.x + (double)z0.y * q0.y +
                     (double)z0.z * q0.z + (double)z0.w * q0.w;
        acc += (double)z1.x * q1.x + (double)z1.y * q1.y +
               (double)z1.z * q1.z + (double)z1.w * q1.w;
        acc += (double)z2.x * q2.x + (double)z2.y * q2.y +
               (double)z2.z * q2.z + (double)z2.w * q2.w;
#pragma unroll
        for (int o = 32; o > 0; o >>= 1) acc += __shfl_xor(acc, o);
        if (lane == 0) sim[b * NPIX + row] = (float)acc / rt;
    }
}

// ---------------------------------------------------------------------------
// Lock-free union-find in LDS with path halving (round-12 ablation: unions
// throughput-free; structure proven absmax-0 since round 3).
// ---------------------------------------------------------------------------
__device__ inline int uf_find(volatile int* p, int x) {
    int px = p[x];
    while (px != x) {
        const int g = p[px];
        if (g != px) p[x] = g;   // path halving (benign race)
        x = g;
        px = p[x];
    }
    return x;
}

__device__ inline void uf_union(volatile int* p, int a, int b) {
    while (true) {
        a = uf_find(p, a);
        b = uf_find(p, b);
        if (a == b) return;
        const int hi = a > b ? a : b;
        const int lo = a ^ b ^ hi;
        const int old = atomicCAS((int*)&p[hi], hi, lo);
        if (old == hi) return;
        a = old; b = lo;
    }
}

__device__ inline unsigned long long umax64(unsigned long long a,
                                            unsigned long long b) {
    return a > b ? a : b;
}
__device__ inline unsigned long long umin64(unsigned long long a,
                                            unsigned long long b) {
    return a < b ? a : b;
}

// ---------------------------------------------------------------------------
// Kernel 2: 256 threads x 4 px, skeleton-minimized: 8 barriers (was ~18),
// ZERO serial t==0 sections (all cross-wave combines are redundant all-thread
// reads of 4 wave-partials), per-wave hist/area/ssum (contention /4), packed
// u8 in LDS replaces the atomicOr bitmap, top-4 via per-thread sort4 +
// in-wave bitonic merge (round-13-verified) + one LDS exchange.
// ---------------------------------------------------------------------------
__global__ __launch_bounds__(256) void sgatt_region(const float* __restrict__ sim,
                                                    float* __restrict__ out) {
    const int b    = blockIdx.x;
    const int t    = threadIdx.x;
    const int lane = t & 63;
    const int wid  = t >> 6;

    __shared__ int   s_par[NPIX];                 // 4 KB
    __shared__ int   s_hist[4 * 256];             // 4 KB  (per-wave)
    __shared__ unsigned int s_u8p[256];           // 1 KB  (packed u8 x4)
    __shared__ int   s_areaw[4 * NPIX];           // 16 KB (per-wave)
    __shared__ float s_ssumw[4 * NPIX];           // 16 KB (per-wave)
    __shared__ float s_wA[4], s_wB[4];
    __shared__ float s_avv[4];
    __shared__ int   s_avi[4];
    __shared__ unsigned long long s_part[16];

    // ---- phase 1: load sim, wave min/max partials; zero LDS -------------
    const float4 sv4 =
        reinterpret_cast<const float4*>(sim + (size_t)b * NPIX)[t];
    const float svj[4] = {sv4.x, sv4.y, sv4.z, sv4.w};
    {
        float mn = fminf(fminf(svj[0], svj[1]), fminf(svj[2], svj[3]));
        float mx = fmaxf(fmaxf(svj[0], svj[1]), fmaxf(svj[2], svj[3]));
#pragma unroll
        for (int o = 32; o > 0; o >>= 1) {
            mn = fminf(mn, __shfl_xor(mn, o));
            mx = fmaxf(mx, __shfl_xor(mx, o));
        }
        if (lane == 0) { s_wA[wid] = mn; s_wB[wid] = mx; }
    }
#pragma unroll
    for (int k = 0; k < 4; ++k) s_hist[t + 256 * k] = 0;
#pragma unroll
    for (int k = 0; k < 16; ++k) {
        s_areaw[t + 256 * k] = 0;
        s_ssumw[t + 256 * k] = 0.0f;
    }
    __syncthreads();                                            // (1)

    // all-thread combine (no t==0 section)
    float smin = s_wA[0], smax = s_wB[0];
#pragma unroll
    for (int w = 1; w < 4; ++w) {
        smin = fminf(smin, s_wA[w]);
        smax = fmaxf(smax, s_wB[w]);
    }

    // ---- phase 2: sal + u8 (exact fp32, no FMA); pack u8; per-wave hist --
    const float den0 = __fadd_rn(__fsub_rn(smax, smin), 1e-6f);
    float salj[4];
    int u8j[4];
#pragma unroll
    for (int j = 0; j < 4; ++j) {
        salj[j] = __fdiv_rn(__fsub_rn(svj[j], smin), den0);
        int u = (int)floorf(__fmul_rn(salj[j], 255.0f));
        u8j[j] = min(max(u, 0), 255);
    }
    s_u8p[t] = (unsigned)u8j[0] | ((unsigned)u8j[1] << 8) |
               ((unsigned)u8j[2] << 16) | ((unsigned)u8j[3] << 24);
    {
        int* hw = s_hist + wid * 256;
#pragma unroll
        for (int j = 0; j < 4; ++j) atomicAdd(&hw[u8j[j]], 1);
    }
    __syncthreads();                                            // (2)

    // ---- phase 3: Otsu. Exact fp32 cumsums (multiples of 2^-10, numerators
    // < 2^24, any association). Thread t owns bin t.
    int thr;
    {
        const int hsum = s_hist[t] + s_hist[t + 256] + s_hist[t + 512] +
                         s_hist[t + 768];
        const float p = __fmul_rn((float)hsum, 1.0f / 1024.0f);
        float sw = p;
        float sm = __fmul_rn(p, (float)t);
        const float ownw = sw, ownm = sm;
        (void)ownw; (void)ownm;
#pragma unroll
        for (int o = 1; o < 64; o <<= 1) {
            const float aw = __shfl_up(sw, o);
            const float am = __shfl_up(sm, o);
            if (lane >= o) { sw = __fadd_rn(sw, aw); sm = __fadd_rn(sm, am); }
        }
        if (lane == 63) { s_wA[wid] = sw; s_wB[wid] = sm; }
        __syncthreads();                                        // (3)
        // all-thread prefix/total combine (ascending wave order, exact)
        float mut = s_wB[0];
#pragma unroll
        for (int w = 1; w < 4; ++w) mut = __fadd_rn(mut, s_wB[w]);
        for (int w = 0; w < wid; ++w) {
            sw = __fadd_rn(sw, s_wA[w]);
            sm = __fadd_rn(sm, s_wB[w]);
        }
        const float num = __fsub_rn(__fmul_rn(mut, sw), sm);
        const float dnm =
            __fadd_rn(__fmul_rn(sw, __fsub_rn(1.0f, sw)), 1e-12f);
        float bv = __fdiv_rn(__fmul_rn(num, num), dnm);
        int   bi = t;
#pragma unroll
        for (int o = 32; o > 0; o >>= 1) {
            const float v2 = __shfl_xor(bv, o);
            const int   i2 = __shfl_xor(bi, o);
            if (v2 > bv || (v2 == bv && i2 < bi)) { bv = v2; bi = i2; }
        }
        if (lane == 0) { s_avv[wid] = bv; s_avi[wid] = bi; }
        __syncthreads();                                        // (4)
        // all-thread final argmax (ascending wave = ascending bins: strict >
        // keeps first index on ties)
        float fv = s_avv[0];
        int   fi = s_avi[0];
#pragma unroll
        for (int w = 1; w < 4; ++w) {
            const float v2 = s_avv[w];
            const int   i2 = s_avi[w];
            if (v2 > fv || (v2 == fv && i2 < fi)) { fv = v2; fi = i2; }
        }
        thr = fi;
    }

    // ---- phase 4: mask + parent init (W-chain inside quad, plain stores) -
    int mj[4];
#pragma unroll
    for (int j = 0; j < 4; ++j) {
        const int px = 4*t + j;
        mj[j] = (u8j[j] > thr) ? 1 : 0;
        s_par[px] = (j > 0 && mj[j] && mj[j-1]) ? (px - 1) : px;
    }
    __syncthreads();                                            // (5)

    // ---- phase 5: cross-boundary unions (on-check via packed u8) ---------
#define ONPX(p) ((int)((s_u8p[(p) >> 2] >> (((p) & 3) * 8)) & 255u) > thr)
#pragma unroll
    for (int j = 0; j < 4; ++j) {
        if (!mj[j]) continue;
        const int px = 4*t + j;
        const int r = px >> 5, c = px & 31;
        if (j == 0 && c > 0 && ONPX(px - 1)) uf_union(s_par, px, px - 1);
        if (r > 0) {
            if (c > 0 && ONPX(px - 33)) uf_union(s_par, px, px - 33);
            if (ONPX(px - 32))          uf_union(s_par, px, px - 32);
            if (c < 31 && ONPX(px - 31)) uf_union(s_par, px, px - 31);
        }
    }
#undef ONPX
    __syncthreads();                                            // (6)

    // ---- phase 6: lockstep root chase + per-wave accumulate --------------
    int labj[4];
    {
        int cur[4], par[4];
#pragma unroll
        for (int j = 0; j < 4; ++j) cur[j] = 4*t + j;
#pragma unroll
        for (int j = 0; j < 4; ++j) par[j] = s_par[cur[j]];
        while (true) {
            bool any = false;
#pragma unroll
            for (int j = 0; j < 4; ++j) any |= (par[j] != cur[j]);
            if (!any) break;
#pragma unroll
            for (int j = 0; j < 4; ++j) cur[j] = par[j];
#pragma unroll
            for (int j = 0; j < 4; ++j) par[j] = s_par[cur[j]];
        }
#pragma unroll
        for (int j = 0; j < 4; ++j) labj[j] = mj[j] ? (cur[j] + 1) : 0;
    }
    {
        int*   aw = s_areaw + wid * NPIX;
        float* sw = s_ssumw + wid * NPIX;
#pragma unroll
        for (int j = 0; j < 4; ++j) {
            if (mj[j]) {
                atomicAdd(&aw[labj[j] - 1], 1);
                atomicAdd(&sw[labj[j] - 1], salj[j]);
            }
        }
    }
    __syncthreads();                                            // (7)

    // ---- phase 7: top-4. Thread owns labels 4t+1..4t+4: key, sort4,
    // in-wave bitonic merge, one LDS exchange, all-thread 16->4 extract.
    // valid <=> area >= 21; mean > 0 -> float bits order-preserving; ~label
    // in low word -> ties pick lower label (lax.top_k). Keys unique.
    unsigned long long k0 = 0, k1 = 0, k2 = 0, k3 = 0;
    {
        unsigned long long kk[4];
#pragma unroll
        for (int j = 0; j < 4; ++j) {
            const int idx = 4*t + j;               // label = idx+1
            const int a = s_areaw[idx] + s_areaw[idx + NPIX] +
                          s_areaw[idx + 2*NPIX] + s_areaw[idx + 3*NPIX];
            kk[j] = 0ull;
            if (a >= 21) {
                const float ss =
                    __fadd_rn(__fadd_rn(s_ssumw[idx], s_ssumw[idx + NPIX]),
                              __fadd_rn(s_ssumw[idx + 2*NPIX],
                                        s_ssumw[idx + 3*NPIX]));
                const float mean = __fdiv_rn(ss, (float)a);
                kk[j] = ((unsigned long long)__float_as_uint(mean) << 32) |
                        (unsigned long long)(0xFFFFFFFFu - (unsigned)(idx + 1));
            }
        }
        // sort 4 desc (network: (01)(23)(02)(13)(12))
        unsigned long long a0, a1;
        a0 = umax64(kk[0], kk[1]); a1 = umin64(kk[0], kk[1]);
        kk[0] = a0; kk[1] = a1;
        a0 = umax64(kk[2], kk[3]); a1 = umin64(kk[2], kk[3]);
        kk[2] = a0; kk[3] = a1;
        a0 = umax64(kk[0], kk[2]); a1 = umin64(kk[0], kk[2]);
        kk[0] = a0; kk[2] = a1;
        a0 = umax64(kk[1], kk[3]); a1 = umin64(kk[1], kk[3]);
        kk[1] = a0; kk[3] = a1;
        a0 = umax64(kk[1], kk[2]); a1 = umin64(kk[1], kk[2]);
        kk[1] = a0; kk[2] = a1;
        k0 = kk[0]; k1 = kk[1]; k2 = kk[2]; k3 = kk[3];
    }
#pragma unroll
    for (int o = 32; o > 0; o >>= 1) {
        const unsigned long long p0 = __shfl_xor(k0, o);
        const unsigned long long p1 = __shfl_xor(k1, o);
        const unsigned long long p2 = __shfl_xor(k2, o);
        const unsigned long long p3 = __shfl_xor(k3, o);
        const unsigned long long t0 = umax64(k0, p3);
        const unsigned long long t1 = umax64(k1, p2);
        const unsigned long long t2 = umax64(k2, p1);
        const unsigned long long t3 = umax64(k3, p0);
        const unsigned long long u0 = umax64(t0, t2), u2 = umin64(t0, t2);
        const unsigned long long u1 = umax64(t1, t3), u3 = umin64(t1, t3);
        k0 = umax64(u0, u1); k1 = umin64(u0, u1);
        k2 = umax64(u2, u3); k3 = umin64(u2, u3);
    }
    if (lane == 0) {
        s_part[wid * 4 + 0] = k0;
        s_part[wid * 4 + 1] = k1;
        s_part[wid * 4 + 2] = k2;
        s_part[wid * 4 + 3] = k3;
    }
    __syncthreads();                                            // (8)
    int tlv[KTOP];
    {
        unsigned long long kk[16];
#pragma unroll
        for (int i = 0; i < 16; ++i) kk[i] = s_part[i];
#pragma unroll
        for (int k = 0; k < KTOP; ++k) {
            unsigned long long v = kk[0];
#pragma unroll
            for (int i = 1; i < 16; ++i) v = umax64(v, kk[i]);
            tlv[k] = v ? (int)(0xFFFFFFFFu - (unsigned)(v & 0xFFFFFFFFull))
                       : -1;
#pragma unroll
            for (int i = 0; i < 16; ++i)
                if (kk[i] == v && v != 0ull) kk[i] = 0ull;
        }
    }

    // ---- phase 8: write regions + background (float4 stores) -------------
    float* ob = out + (size_t)b * 5 * NPIX;
    int anyr[4] = {0, 0, 0, 0};
#pragma unroll
    for (int k = 0; k < KTOP; ++k) {
        const int tlk = tlv[k];
        float4 o;
        float* op = reinterpret_cast<float*>(&o);
#pragma unroll
        for (int j = 0; j < 4; ++j) {
            const int match = (tlk >= 0 && labj[j] == tlk) ? 1 : 0;
            anyr[j] |= match;
            op[j] = (float)match;
        }
        reinterpret_cast<float4*>(ob + (size_t)k * NPIX)[t] = o;
    }
    {
        float4 o;
        float* op = reinterpret_cast<float*>(&o);
#pragma unroll
        for (int j = 0; j < 4; ++j) op[j] = anyr[j] ? 0.0f : 1.0f;
        reinterpret_cast<float4*>(ob + (size_t)KTOP * NPIX)[t] = o;
    }
}

// ---------------------------------------------------------------------------
extern "C" void kernel_launch(void* const* d_in, const int* in_sizes, int n_in,
                              void* d_out, int out_size, void* d_ws, size_t ws_size,
                              hipStream_t stream) {
    const float* z = (const float*)d_in[0];
    const float* q = (const float*)d_in[1];
    float* out = (float*)d_out;
    float* sim = (float*)d_ws;  // NB*NPIX floats = 256 KiB

    dim3 g1(NPIX / 16, NB);
    sgatt_sim<<<g1, 256, 0, stream>>>(z, q, sim);
    sgatt_region<<<NB, 256, 0, stream>>>(sim, out);
}